// Round 10
// baseline (282.306 us; speedup 1.0000x reference)
//
#include <hip/hip_runtime.h>
#include <cstdint>

#define BB 2
#define NN 16384
#define MM 4096
#define CF 256
#define CT 128
#define CP 64
#define NSEG 16
#define SEGSZ 256

// ================= kernel 0: counting-sort refs & queries by x =================
// Round-10 rewrite of the R9 sort (measured 110.8 us, 0.08% occupancy, 6494
// LDS bank conflicts): the LDS histogram atomics serialized on hot center
// bins and the tid==0 prefix scan was serial. Fixes, same 4-block grid:
//  - per-wave privatized histograms whist[8][256] -> same-address atomic
//    serialization / 8 (both count and scatter passes);
//  - Hillis-Steele parallel exclusive scan (8 barrier rounds) for bin bases;
//  - per-(wave,bin) scatter cursors derived from the scan.
// Within-bin order is atomic-nondeterministic (and differs from R9) —
// harmless: the knn network is fully lexicographic in (d, j), so the output
// is provably scatter-order-independent.
__global__ __launch_bounds__(512) void sort_kernel(
    const float* __restrict__ coords,      // [B,N,3]
    const float* __restrict__ ref_coords,  // [B,M,3]
    float4* __restrict__ sR,               // [B,M] sorted pre-doubled refs
    int*    __restrict__ sJ,               // [B,M] original ref index
    int*    __restrict__ sQ,               // [B,N] query order
    float2* __restrict__ segB)             // [B,16] conservative seg x-range
{
#pragma clang fp contract(off)
    __shared__ int whist[8][256];   // per-wave privatized histograms (8 KB)
    __shared__ int tot[256];
    __shared__ int base_[257];
    const int tid = threadIdx.x;
    const int wv  = tid >> 6;
    const int b   = blockIdx.y;
    const bool doRefs = (blockIdx.x == 0);
    const int count = doRefs ? MM : NN;
    const float* src = doRefs ? (ref_coords + (size_t)b * MM * 3)
                              : (coords     + (size_t)b * NN * 3);

    for (int k = tid; k < 8 * 256; k += 512) ((int*)whist)[k] = 0;
    __syncthreads();

    // pass 1: count (per-wave private copy -> hot-bin serialization /8)
    for (int e = tid; e < count; e += 512) {
        const float x = src[3 * e];
        int bin = (int)((x + 4.5f) * (256.0f / 9.0f));
        bin = bin < 0 ? 0 : (bin > 255 ? 255 : bin);
        atomicAdd(&whist[wv][bin], 1);
    }
    __syncthreads();

    // per-bin totals (tid<256 owns bin tid)
    if (tid < 256) {
        int acc = 0;
        #pragma unroll
        for (int w = 0; w < 8; ++w) acc += whist[w][tid];
        tot[tid] = acc;
        base_[tid + 1] = acc;
    }
    if (tid == 0) base_[0] = 0;
    __syncthreads();

    // Hillis-Steele inclusive scan over base_[1..256] -> exclusive bin bases
    for (int off = 1; off < 256; off <<= 1) {
        int v = 0;
        if (tid < 256) {
            v = base_[tid + 1];
            if (tid + 1 > off) v += base_[tid + 1 - off];
        }
        __syncthreads();
        if (tid < 256) base_[tid + 1] = v;
        __syncthreads();
    }

    // per-(wave,bin) scatter cursors: whist[w][bin] := base_[bin] + sum_{w'<w}
    if (tid < 256) {
        int run = base_[tid];
        #pragma unroll
        for (int w = 0; w < 8; ++w) {
            const int t = whist[w][tid];
            whist[w][tid] = run;
            run += t;
        }
    }
    __syncthreads();

    // pass 2: scatter via private cursors
    for (int e = tid; e < count; e += 512) {
        const float x = src[3 * e];
        int bin = (int)((x + 4.5f) * (256.0f / 9.0f));
        bin = bin < 0 ? 0 : (bin > 255 ? 255 : bin);
        const int pos = atomicAdd(&whist[wv][bin], 1);
        if (doRefs) {
            const float y = src[3 * e + 1];
            const float z = src[3 * e + 2];
            // identical math to the proven staging: pre-doubled xyz (exact),
            // rr from ORIGINAL coords in numpy sum order
            sR[(size_t)b * MM + pos] = make_float4(x + x, y + y, z + z,
                                                   (x * x + y * y) + z * z);
            sJ[(size_t)b * MM + pos] = e;
        } else {
            sQ[(size_t)b * NN + pos] = e;
        }
    }
    __syncthreads();

    if (doRefs && tid == 0) {
        // conservative per-segment x-range from analytic bin edges
        for (int sg = 0; sg < NSEG; ++sg) {
            const int plo = sg * SEGSZ, phi = plo + SEGSZ - 1;
            int blo = 0; while (base_[blo + 1] <= plo) ++blo;
            int bhi = blo; while (base_[bhi + 1] <= phi) ++bhi;
            float xlo = (blo == 0)   ? -1e30f : (blo * (9.0f / 256.0f) - 4.5f);
            float xhi = (bhi == 255) ?  1e30f : ((bhi + 1) * (9.0f / 256.0f) - 4.5f);
            segB[b * NSEG + sg] = make_float2(xlo, xhi);
        }
    }
}

// ======================= kernel 1: 3-NN (pruned scan) =======================
// BYTE-IDENTICAL to round 9 — its counters never surfaced (sort monopolized
// the top-5); this round they will, attributing the pruning question cleanly.
// Pre-committed decision rule: >=60 us next round => pruning falsified,
// revert to the proven R7 pair.
#define TPB1 512

__global__ __launch_bounds__(TPB1, 4) void knn_kernel(
    const float* __restrict__ coords,      // [B,N,3]
    const float4* __restrict__ sR,         // [B,M] sorted refs
    const int*   __restrict__ sJ,          // [B,M] orig ref idx
    const int*   __restrict__ sQ,          // [B,N] query order
    const float2* __restrict__ segB,       // [B,16]
    int4* __restrict__ wsI,                // [B,N] {i0,i1,i2,-}
    float4* __restrict__ wsW)              // [B,N] {w0,w1,w2,-}
{
#pragma clang fp contract(off)
    __shared__ float4 sref[MM];      // 64 KB
    __shared__ int    sjj[MM];       // 16 KB

    const int tid = threadIdx.x;
    const int b   = blockIdx.y;

    for (int e = tid; e < MM; e += TPB1) {
        sref[e] = sR[(size_t)b * MM + e];
        sjj[e]  = sJ[(size_t)b * MM + e];
    }
    __syncthreads();

    const int pl = tid >> 3;            // query-in-block 0..63 (sorted order)
    const int s  = tid & 7;             // sub-lane 0..7
    const int p  = blockIdx.x * 64 + pl;
    const int qi = sQ[(size_t)b * NN + p];   // original query index

    const float* cp = coords + ((size_t)b * NN + qi) * 3;
    const float cx = cp[0];
    const float cy = cp[1];
    const float cz = cp[2];
    const float cc = (cx * cx + cy * cy) + cz * cz;   // numpy sum order

    float d0 = INFINITY, d1 = INFINITY, d2v = INFINITY;
    int   i0 = 0, i1 = 0, i2 = 0;
    float tau = INFINITY;               // 8-lane pruning threshold
    float thr = INFINITY;               // min(d2v, tau)

    // wave-uniform start segment from a representative query x
    const float xr = __shfl(cx, 32, 64);
    const float2* sb = segB + b * NSEG;
    int seg0 = 0;
    #pragma unroll
    for (int k = 1; k < NSEG; ++k) seg0 += (sb[k].x <= xr) ? 1 : 0;

    // visit segments center-outward: 0, +1, -1, +2, -2, ...
    for (int t = 0; t < 2 * NSEG - 1; ++t) {
        const int o   = (t & 1) ? ((t >> 1) + 1) : -(t >> 1);
        const int seg = seg0 + o;
        if (seg < 0 || seg >= NSEG) continue;

        const float2 be = sb[seg];
        const float dxm = fmaxf(0.0f, fmaxf(be.x - cx, cx - be.y));
        if (__all(dxm * dxm - 1e-4f > thr)) continue;   // provably dead segment

        const int ebase = seg * SEGSZ + s;
        #pragma unroll 4
        for (int k = 0; k < 32; ++k) {
            const int e = ebase + (k << 3);
            const float4 r = sref[e];
            // dot2 == 2*((cx*rx + cy*ry) + cz*rz) bit-exactly (pre-doubled)
            const float dot2 = (cx * r.x + cy * r.y) + cz * r.z;
            const float dd   = (cc + r.w) - dot2;        // == numpy d2
            if (__any(dd <= thr)) {
                const int j = sjj[e];
                // lexicographic (d, j): permuted order, lower j wins ties
                const bool l0 = (dd < d0)  || (dd == d0  && j < i0);
                const bool l1 = (dd < d1)  || (dd == d1  && j < i1);
                const bool l2 = (dd < d2v) || (dd == d2v && j < i2);
                i2 = l2 ? (l1 ? i1 : j) : i2;
                i1 = l1 ? (l0 ? i0 : j) : i1;
                i0 = l0 ? j : i0;
                const float n2  = __builtin_amdgcn_fmed3f(dd, d1, d2v);
                const float n1  = __builtin_amdgcn_fmed3f(dd, d0, d1);
                const float nv0 = fminf(dd, d0);
                d2v = n2; d1 = n1; d0 = nv0;
                thr = fminf(d2v, tau);
            }
        }
        // refresh tau = min of this query's 8 sub-lanes' d2v (R2 cadence)
        float tt = d2v;
        tt = fminf(tt, __shfl_xor(tt, 1, 64));
        tt = fminf(tt, __shfl_xor(tt, 2, 64));
        tt = fminf(tt, __shfl_xor(tt, 4, 64));
        tau = tt;
        thr = fminf(d2v, tau);
    }

    // lexicographic (d, idx) merge across the 8 sub-lanes (proven)
    auto ins = [&](float e, int f) {
        const bool l2 = (e < d2v) || (e == d2v && f < i2);
        const bool l1 = (e < d1)  || (e == d1  && f < i1);
        const bool l0 = (e < d0)  || (e == d0  && f < i0);
        d2v = l2 ? (l1 ? d1 : e) : d2v;  i2 = l2 ? (l1 ? i1 : f) : i2;
        d1  = l1 ? (l0 ? d0 : e) : d1;   i1 = l1 ? (l0 ? i0 : f) : i1;
        d0  = l0 ? e : d0;               i0 = l0 ? f : i0;
    };
    for (int off = 1; off < 8; off <<= 1) {
        const float e0 = __shfl_xor(d0,  off, 64);
        const float e1 = __shfl_xor(d1,  off, 64);
        const float e2 = __shfl_xor(d2v, off, 64);
        const int   f0 = __shfl_xor(i0,  off, 64);
        const int   f1 = __shfl_xor(i1,  off, 64);
        const int   f2 = __shfl_xor(i2,  off, 64);
        ins(e0, f0);
        ins(e1, f1);
        ins(e2, f2);
    }

    if (s == 0) {
        float w0 = 1.0f / (d0  + 1e-8f);     // IEEE divs, numpy order
        float w1 = 1.0f / (d1  + 1e-8f);
        float w2 = 1.0f / (d2v + 1e-8f);
        const float sum = (w0 + w1) + w2;
        wsI[(size_t)b * NN + qi] = make_int4(i0, i1, i2, 0);
        wsW[(size_t)b * NN + qi] = make_float4(w0 / sum, w1 / sum, w2 / sum, 0.0f);
    }
}

// ===================== kernel 2: row-staged interpolation ====================
// EXACT round-3 kernel — measured-best interp (~24 us). Unchanged.
#define TPB2 512
#define NIB  (BB * (CF + CT) / 2)   // 384 interp blocks (2 rows each)
#define NCB  32                     // copy blocks (4 pf rows each)

__global__ __launch_bounds__(TPB2, 8) void interp_kernel(
    const float* __restrict__ refF,        // [B,256,M]
    const float* __restrict__ refT,        // [B,128,M]
    const float* __restrict__ pf,          // [B,64,N]
    const int4*  __restrict__ wsI,         // [B,N]
    const float4* __restrict__ wsW,        // [B,N]
    float* __restrict__ out)               // [B,320,N] ++ [B,128,N]
{
#pragma clang fp contract(off)
    __shared__ float rowA[MM];             // 16 KB
    __shared__ float rowB[MM];             // 16 KB
    const int tid  = threadIdx.x;
    const int task = blockIdx.x;
    const size_t outT_base = (size_t)BB * (CF + CP) * NN;

    if (task >= NIB) {                     // -------- pf copy blocks --------
        const int t3 = task - NIB;         // 0..31, 4 rows each
        for (int j = 0; j < 4; ++j) {
            const int r  = t3 * 4 + j;
            const int bb = r >> 6;
            const int c  = r & (CP - 1);
            const float4* s4 = (const float4*)(pf + ((size_t)bb * CP + c) * NN);
            float4* d4 = (float4*)(out + ((size_t)bb * (CF + CP) + CF + c) * NN);
            for (int i = tid; i < NN / 4; i += TPB2) d4[i] = s4[i];
        }
        return;                            // block-uniform exit
    }

    const int r0 = task * 2;               // rows r0, r0+1 (same b, same class)
    const float* src0;
    float* dst0;
    int b;
    if (r0 < BB * CF) {                    // interpolated features
        b = r0 >> 8;
        const int c = r0 & (CF - 1);
        src0 = refF + ((size_t)b * CF + c) * MM;
        dst0 = out + ((size_t)b * (CF + CP) + c) * NN;
    } else {                               // interpolated t_embed
        const int r2 = r0 - BB * CF;
        b = r2 >> 7;
        const int c = r2 & (CT - 1);
        src0 = refT + ((size_t)b * CT + c) * MM;
        dst0 = out + outT_base + ((size_t)b * CT + c) * NN;
    }
    const float* src1 = src0 + MM;
    float* dst1 = dst0 + NN;

    for (int i = tid; i < MM / 4; i += TPB2) {
        ((float4*)rowA)[i] = ((const float4*)src0)[i];
        ((float4*)rowB)[i] = ((const float4*)src1)[i];
    }
    __syncthreads();

    const int4*   wi = wsI + (size_t)b * NN;
    const float4* ww = wsW + (size_t)b * NN;

    auto clampi = [](int v) { return v < 0 ? 0 : (v > MM - 1 ? MM - 1 : v); };

    int4   id = wi[tid];
    float4 w  = ww[tid];
    for (int nq = tid; nq < NN; nq += TPB2) {
        const int nq2 = nq + TPB2;
        int4   idn;
        float4 wn;
        if (nq2 < NN) { idn = wi[nq2]; wn = ww[nq2]; }   // prefetch next
        const int a0 = clampi(id.x), a1 = clampi(id.y), a2 = clampi(id.z);
        dst0[nq] = (w.x * rowA[a0] + w.y * rowA[a1]) + w.z * rowA[a2];
        dst1[nq] = (w.x * rowB[a0] + w.y * rowB[a1]) + w.z * rowB[a2];
        id = idn; w = wn;
    }
}

extern "C" void kernel_launch(void* const* d_in, const int* in_sizes, int n_in,
                              void* d_out, int out_size, void* d_ws, size_t ws_size,
                              hipStream_t stream) {
    const float* coords     = (const float*)d_in[0];
    const float* ref_coords = (const float*)d_in[1];
    const float* refF       = (const float*)d_in[2];
    const float* refT       = (const float*)d_in[3];
    const float* pf         = (const float*)d_in[4];
    float* out = (float*)d_out;

    // ws layout (16B-aligned blocks): sR | sJ | sQ | segB | wsI | wsW
    char* w = (char*)d_ws;
    float4* sR   = (float4*)w;                 w += (size_t)BB * MM * sizeof(float4);
    int*    sJ   = (int*)w;                    w += (size_t)BB * MM * sizeof(int);
    int*    sQ   = (int*)w;                    w += (size_t)BB * NN * sizeof(int);
    float2* segB = (float2*)w;                 w += (size_t)BB * NSEG * sizeof(float2);
    int4*   wsI  = (int4*)w;                   w += (size_t)BB * NN * sizeof(int4);
    float4* wsW  = (float4*)w;

    hipLaunchKernelGGL(sort_kernel, dim3(2, BB), dim3(512), 0, stream,
                       coords, ref_coords, sR, sJ, sQ, segB);
    hipLaunchKernelGGL(knn_kernel, dim3(NN / 64, BB), dim3(TPB1), 0, stream,
                       coords, sR, sJ, sQ, segB, wsI, wsW);
    hipLaunchKernelGGL(interp_kernel, dim3(NIB + NCB), dim3(TPB2), 0, stream,
                       refF, refT, pf, wsI, wsW, out);
}

// Round 11
// 161.431 us; speedup vs baseline: 1.7488x; 1.7488x over previous
//
#include <hip/hip_runtime.h>
#include <cstdint>

#define BB 2
#define NN 16384
#define MM 4096
#define CF 256
#define CT 128
#define CP 64

// ======================= kernel 1: 3-NN -> workspace =======================
// EXACT round-2/round-7 kernel — the measured-best knn (70.0 us, VGPR 16,
// LDS 32768, Occupancy ~35%). Six structural variants (wider gate, branchless
// Q=2, split-K occupancy, uniform-load, x-sorted pruning) all regressed or
// failed to attribute; this config is the proven floor of the brute-force
// structure (LDS pipe ~41us + VALU ~24us, partially overlapped). DO NOT VARY.
#define TPB1 512
#define NPB1 64
#define CHUNK 2048

__global__ __launch_bounds__(TPB1, 4) void knn_kernel(
    const float* __restrict__ coords,      // [B,N,3]
    const float* __restrict__ ref_coords,  // [B,M,3]
    int4* __restrict__ wsI,                // [B,N] {i0,i1,i2,-}
    float4* __restrict__ wsW)              // [B,N] {w0,w1,w2,-}
{
#pragma clang fp contract(off)
    __shared__ float4 refs[CHUNK];      // 32 KB (2x, 2y, 2z, rr)

    const int tid = threadIdx.x;
    const int b   = blockIdx.y;
    const int n0  = blockIdx.x * NPB1;

    const int pl = tid >> 3;            // point-in-block 0..63
    const int s  = tid & 7;             // sub-lane 0..7
    const int n  = n0 + pl;

    const float* cp = coords + ((size_t)b * NN + n) * 3;
    const float cx = cp[0];
    const float cy = cp[1];
    const float cz = cp[2];
    const float cc = (cx * cx + cy * cy) + cz * cz;   // numpy sum order

    float d0 = INFINITY, d1 = INFINITY, d2v = INFINITY;
    int   i0 = 0, i1 = 0, i2 = 0;
    float tau = INFINITY;               // group pruning threshold
    float thr = INFINITY;               // min(d2v, tau), kept in a register

    const float* rc = ref_coords + (size_t)b * MM * 3;

    for (int ch = 0; ch < MM / CHUNK; ++ch) {
        __syncthreads();                 // refs[] reuse guard
        for (int e = tid; e < CHUNK; e += TPB1) {
            const int j = ch * CHUNK + e;
            const float x = rc[3 * j + 0];
            const float y = rc[3 * j + 1];
            const float z = rc[3 * j + 2];
            // rr from ORIGINAL coords (numpy order); xyz pre-doubled (exact)
            refs[e] = make_float4(x + x, y + y, z + z, (x * x + y * y) + z * z);
        }
        __syncthreads();

        const int jbase = ch * CHUNK;
        for (int it0 = 0; it0 < CHUNK / 8; it0 += 32) {
            #pragma unroll 4
            for (int k = 0; k < 32; ++k) {
                const int e = s + ((it0 + k) << 3);
                const float4 r = refs[e];
                // dot2 == 2*((cx*rx + cy*ry) + cz*rz) bit-exactly
                const float dot2 = (cx * r.x + cy * r.y) + cz * r.z;
                const float dd   = (cc + r.w) - dot2;        // == numpy d2
                // Wave-uniform skip: if no lane beats its threshold, every
                // lane's dd is provably dead (>= d2v local no-op, or >= tau
                // globally dominated). Body is the ORIGINAL exact update.
                if (__any(dd < thr)) {
                    const int j = jbase + e;
                    const bool l2 = dd < d2v;
                    const bool l1 = dd < d1;
                    const bool l0 = dd < d0;
                    i2 = l2 ? (l1 ? i1 : j) : i2;
                    i1 = l1 ? (l0 ? i0 : j) : i1;
                    i0 = l0 ? j : i0;
                    const float n2  = __builtin_amdgcn_fmed3f(dd, d1, d2v);
                    const float n1  = __builtin_amdgcn_fmed3f(dd, d0, d1);
                    const float nv0 = fminf(dd, d0);
                    d2v = n2; d1 = n1; d0 = nv0;
                    thr = fminf(d2v, tau);
                }
            }
            // refresh tau = min of the 8 lanes' (same query) d2v
            float t = d2v;
            t = fminf(t, __shfl_xor(t, 1, 64));
            t = fminf(t, __shfl_xor(t, 2, 64));
            t = fminf(t, __shfl_xor(t, 4, 64));
            tau = t;
            thr = fminf(d2v, tau);
        }
    }

    // lexicographic (d, idx) insert: lower index wins exact ties (stable top_k)
    auto ins = [&](float e, int f) {
        const bool l2 = (e < d2v) || (e == d2v && f < i2);
        const bool l1 = (e < d1)  || (e == d1  && f < i1);
        const bool l0 = (e < d0)  || (e == d0  && f < i0);
        d2v = l2 ? (l1 ? d1 : e) : d2v;  i2 = l2 ? (l1 ? i1 : f) : i2;
        d1  = l1 ? (l0 ? d0 : e) : d1;   i1 = l1 ? (l0 ? i0 : f) : i1;
        d0  = l0 ? e : d0;               i0 = l0 ? f : i0;
    };

    // butterfly across the 8 sub-lanes (xor<8 stays in-group, in-wave)
    for (int off = 1; off < 8; off <<= 1) {
        const float e0 = __shfl_xor(d0,  off, 64);
        const float e1 = __shfl_xor(d1,  off, 64);
        const float e2 = __shfl_xor(d2v, off, 64);
        const int   f0 = __shfl_xor(i0,  off, 64);
        const int   f1 = __shfl_xor(i1,  off, 64);
        const int   f2 = __shfl_xor(i2,  off, 64);
        ins(e0, f0);
        ins(e1, f1);
        ins(e2, f2);
    }

    if (s == 0) {
        float w0 = 1.0f / (d0  + 1e-8f);     // IEEE divs, numpy order
        float w1 = 1.0f / (d1  + 1e-8f);
        float w2 = 1.0f / (d2v + 1e-8f);
        const float sum = (w0 + w1) + w2;
        wsI[(size_t)b * NN + n] = make_int4(i0, i1, i2, 0);
        wsW[(size_t)b * NN + n] = make_float4(w0 / sum, w1 / sum, w2 / sum, 0.0f);
    }
}

// ===================== kernel 2: row-staged interpolation ====================
// Round-11 interp: per-CU cost model says the dominant term is the random
// ds_read_b32 gather (~1536 wave-reads/block x ~5.8cyc x ~2.7x random-bank
// conflicts ~ 16us), not the write stream. Two stacked fixes, same 32 KB LDS:
//  (1) rows INTERLEAVED in LDS (rowAB[a] = {rowA[a], rowB[a]}): both rows'
//      gathers at index a become ONE ds_read_b64 -> gather instrs per query
//      drop 6 -> 3;
//  (2) 2 queries per thread + float2 coalesced stores (G13): store instrs
//      and loop bookkeeping halve, iterations 32 -> 16.
// FMA expressions and order identical (contract off) -> bit-identical output.
#define TPB2 512
#define NIB  (BB * (CF + CT) / 2)   // 384 interp blocks (2 rows each)
#define NCB  32                     // copy blocks (4 pf rows each)

__global__ __launch_bounds__(TPB2, 8) void interp_kernel(
    const float* __restrict__ refF,        // [B,256,M]
    const float* __restrict__ refT,        // [B,128,M]
    const float* __restrict__ pf,          // [B,64,N]
    const int4*  __restrict__ wsI,         // [B,N]
    const float4* __restrict__ wsW,        // [B,N]
    float* __restrict__ out)               // [B,320,N] ++ [B,128,N]
{
#pragma clang fp contract(off)
    __shared__ float2 rowAB[MM];           // 32 KB, rows interleaved
    const int tid  = threadIdx.x;
    const int task = blockIdx.x;
    const size_t outT_base = (size_t)BB * (CF + CP) * NN;

    if (task >= NIB) {                     // -------- pf copy blocks --------
        const int t3 = task - NIB;         // 0..31, 4 rows each
        for (int j = 0; j < 4; ++j) {
            const int r  = t3 * 4 + j;
            const int bb = r >> 6;
            const int c  = r & (CP - 1);
            const float4* s4 = (const float4*)(pf + ((size_t)bb * CP + c) * NN);
            float4* d4 = (float4*)(out + ((size_t)bb * (CF + CP) + CF + c) * NN);
            for (int i = tid; i < NN / 4; i += TPB2) d4[i] = s4[i];
        }
        return;                            // block-uniform exit
    }

    const int r0 = task * 2;               // rows r0, r0+1 (same b, same class)
    const float* src0;
    float* dst0;
    int b;
    if (r0 < BB * CF) {                    // interpolated features
        b = r0 >> 8;
        const int c = r0 & (CF - 1);
        src0 = refF + ((size_t)b * CF + c) * MM;
        dst0 = out + ((size_t)b * (CF + CP) + c) * NN;
    } else {                               // interpolated t_embed
        const int r2 = r0 - BB * CF;
        b = r2 >> 7;
        const int c = r2 & (CT - 1);
        src0 = refT + ((size_t)b * CT + c) * MM;
        dst0 = out + outT_base + ((size_t)b * CT + c) * NN;
    }
    const float* src1 = src0 + MM;
    float* dst1 = dst0 + NN;

    // stage both rows interleaved: rowAB[a] = {row0[a], row1[a]}
    for (int i = tid; i < MM / 4; i += TPB2) {
        const float4 a4 = ((const float4*)src0)[i];
        const float4 b4 = ((const float4*)src1)[i];
        ((float4*)rowAB)[2 * i + 0] = make_float4(a4.x, b4.x, a4.y, b4.y);
        ((float4*)rowAB)[2 * i + 1] = make_float4(a4.z, b4.z, a4.w, b4.w);
    }
    __syncthreads();

    const int4*   wi = wsI + (size_t)b * NN;
    const float4* ww = wsW + (size_t)b * NN;

    auto clampi = [](int v) { return v < 0 ? 0 : (v > MM - 1 ? MM - 1 : v); };

    const int q0 = 2 * tid;                // this thread's query pair base
    int4   idA = wi[q0];
    int4   idB = wi[q0 + 1];
    float4 wA  = ww[q0];
    float4 wB  = ww[q0 + 1];
    for (int it = 0; it < NN / (2 * TPB2); ++it) {
        const int nq  = q0 + it * 2 * TPB2;
        const int nqn = nq + 2 * TPB2;
        int4 idA_n, idB_n;
        float4 wA_n, wB_n;
        if (nqn < NN) {                    // prefetch next pair's ws data
            idA_n = wi[nqn]; idB_n = wi[nqn + 1];
            wA_n  = ww[nqn]; wB_n  = ww[nqn + 1];
        }
        const float2 a0 = rowAB[clampi(idA.x)];
        const float2 a1 = rowAB[clampi(idA.y)];
        const float2 a2 = rowAB[clampi(idA.z)];
        const float2 b0 = rowAB[clampi(idB.x)];
        const float2 b1 = rowAB[clampi(idB.y)];
        const float2 b2 = rowAB[clampi(idB.z)];
        float2 prA, prB;                   // prA = row r0 {nq, nq+1}
        prA.x = (wA.x * a0.x + wA.y * a1.x) + wA.z * a2.x;
        prA.y = (wB.x * b0.x + wB.y * b1.x) + wB.z * b2.x;
        prB.x = (wA.x * a0.y + wA.y * a1.y) + wA.z * a2.y;   // row r0+1
        prB.y = (wB.x * b0.y + wB.y * b1.y) + wB.z * b2.y;
        *reinterpret_cast<float2*>(dst0 + nq) = prA;
        *reinterpret_cast<float2*>(dst1 + nq) = prB;
        idA = idA_n; idB = idB_n; wA = wA_n; wB = wB_n;
    }
}

extern "C" void kernel_launch(void* const* d_in, const int* in_sizes, int n_in,
                              void* d_out, int out_size, void* d_ws, size_t ws_size,
                              hipStream_t stream) {
    const float* coords     = (const float*)d_in[0];
    const float* ref_coords = (const float*)d_in[1];
    const float* refF       = (const float*)d_in[2];
    const float* refT       = (const float*)d_in[3];
    const float* pf         = (const float*)d_in[4];
    float* out = (float*)d_out;

    int4*   wsI = (int4*)d_ws;
    float4* wsW = (float4*)((char*)d_ws + (size_t)BB * NN * sizeof(int4));

    hipLaunchKernelGGL(knn_kernel, dim3(NN / NPB1, BB), dim3(TPB1), 0, stream,
                       coords, ref_coords, wsI, wsW);
    hipLaunchKernelGGL(interp_kernel, dim3(NIB + NCB), dim3(TPB2), 0, stream,
                       refF, refT, pf, wsI, wsW, out);
}